// Round 2
// baseline (180.865 us; speedup 1.0000x reference)
//
#include <hip/hip_runtime.h>
#include <math.h>

#define NP 8      // paths
#define ND 128    // D = c / P
#define NC 1024   // channels = NP*ND
#define NL 4096   // sequence length
#define NB 16     // batch
#define CB 4      // batches per chunk (64 MB/chunk -> L3-resident reuse)
#define LN_EPS 1e-5f

// ---------------- Fused kernel: scale chunk (b0s) + pool chunk (b0p) ----------
// Blocks [0, CB*NC)        : out[row] = x[row] * scale[row]  for chunk b0s
// Blocks [CB*NC, 2*CB*NC)  : y[row] = mean_l(x[row])         for chunk b0p
// Either half is disabled by passing b0 < 0.
__global__ __launch_bounds__(256) void pool_scale_kernel(
    const float* __restrict__ x, const float* __restrict__ scale,
    float* __restrict__ out, float* __restrict__ y,
    int b0s, int b0p)
{
    const int blk = blockIdx.x;
    if (blk < CB * NC) {
        if (b0s < 0) return;
        const int row = b0s * NC + blk;
        const float4* xr = (const float4*)(x + (size_t)row * NL);
        float4* orow = (float4*)(out + (size_t)row * NL);
        const float s = scale[row];           // block-uniform -> scalar load
        #pragma unroll
        for (int i = threadIdx.x; i < NL / 4; i += 256) {
            float4 v = xr[i];
            v.x *= s; v.y *= s; v.z *= s; v.w *= s;
            orow[i] = v;
        }
    } else {
        if (b0p < 0) return;
        const int row = b0p * NC + (blk - CB * NC);
        const float4* xr = (const float4*)(x + (size_t)row * NL);
        float s = 0.f;
        #pragma unroll
        for (int i = threadIdx.x; i < NL / 4; i += 256) {
            float4 v = xr[i];
            s += v.x + v.y + v.z + v.w;
        }
        #pragma unroll
        for (int off = 32; off; off >>= 1) s += __shfl_down(s, off, 64);
        __shared__ float sw[4];
        const int lane = threadIdx.x & 63, wid = threadIdx.x >> 6;
        if (lane == 0) sw[wid] = s;
        __syncthreads();
        if (threadIdx.x == 0)
            y[row] = (sw[0] + sw[1] + sw[2] + sw[3]) * (1.f / NL);
    }
}

// ---------------- attn + gate -> scale, for CB batches ----------------
// One block per batch. 1024 threads = one per (p,d).
__global__ __launch_bounds__(1024) void attn_kernel(
    const float* __restrict__ y,
    const float* __restrict__ conv1_w,   // (NP,5)
    const float* __restrict__ conv2_w,   // (NP,9)
    const float* __restrict__ combine_w, // (2,)
    const float* __restrict__ combine_b, // scalar
    const float* __restrict__ ln_g, const float* __restrict__ ln_b,
    const float* __restrict__ W1, const float* __restrict__ b1,  // (NP,2NP),(2NP)
    const float* __restrict__ W2, const float* __restrict__ b2,  // (2NP,NP),(NP)
    float* __restrict__ scale, int b0)
{
    const int b = b0 + blockIdx.x;
    const int tid = threadIdx.x;
    const int p = tid >> 7;      // path
    const int d = tid & 127;     // position in D

    __shared__ float sy[NC];
    __shared__ float sattn[NC];
    __shared__ float sred[16];
    __shared__ float sgate[NP];

    sy[tid] = y[b * NC + tid];
    __syncthreads();

    const float* rowp = sy + p * ND;
    float c1 = 0.f;
    #pragma unroll
    for (int t = 0; t < 5; ++t) {
        int dd = d + t - 2;
        float v = (dd >= 0 && dd < ND) ? rowp[dd] : 0.f;
        c1 += conv1_w[p * 5 + t] * v;
    }
    float c2 = 0.f;
    #pragma unroll
    for (int t = 0; t < 9; ++t) {
        int dd = d + t - 4;
        float v = (dd >= 0 && dd < ND) ? rowp[dd] : 0.f;
        c2 += conv2_w[p * 9 + t] * v;
    }
    const float z = combine_w[0] * c1 + combine_w[1] * c2 + combine_b[0];
    const float a = 1.f / (1.f + expf(-z));
    sattn[tid] = a;

    // per-path mean of attn: each path = 2 consecutive waves of 64
    float r = a;
    #pragma unroll
    for (int off = 32; off; off >>= 1) r += __shfl_down(r, off, 64);
    const int lane = tid & 63, wid = tid >> 6;
    if (lane == 0) sred[wid] = r;
    __syncthreads();

    if (tid == 0) {
        float cross[NP];
        #pragma unroll
        for (int pp = 0; pp < NP; ++pp)
            cross[pp] = (sred[2 * pp] + sred[2 * pp + 1]) * (1.f / ND);
        float mu = 0.f;
        #pragma unroll
        for (int pp = 0; pp < NP; ++pp) mu += cross[pp];
        mu *= (1.f / NP);
        float var = 0.f;
        #pragma unroll
        for (int pp = 0; pp < NP; ++pp) { float dl = cross[pp] - mu; var += dl * dl; }
        var *= (1.f / NP);
        const float inv = rsqrtf(var + LN_EPS);
        float h[NP];
        #pragma unroll
        for (int pp = 0; pp < NP; ++pp)
            h[pp] = (cross[pp] - mu) * inv * ln_g[pp] + ln_b[pp];
        float h2[2 * NP];
        for (int j = 0; j < 2 * NP; ++j) {
            float s = b1[j];
            #pragma unroll
            for (int pp = 0; pp < NP; ++pp) s += h[pp] * W1[pp * (2 * NP) + j];
            h2[j] = 0.5f * s * (1.f + erff(s * 0.70710678118654752f));  // exact GELU
        }
        for (int pp = 0; pp < NP; ++pp) {
            float s = b2[pp];
            #pragma unroll
            for (int j = 0; j < 2 * NP; ++j) s += h2[j] * W2[j * NP + pp];
            sgate[pp] = 1.f / (1.f + expf(-s));
        }
    }
    __syncthreads();

    scale[b * NC + tid] = sattn[tid] * sgate[p];
}

extern "C" void kernel_launch(void* const* d_in, const int* in_sizes, int n_in,
                              void* d_out, int out_size, void* d_ws, size_t ws_size,
                              hipStream_t stream) {
    const float* x         = (const float*)d_in[0];
    const float* conv1_w   = (const float*)d_in[1];
    const float* conv2_w   = (const float*)d_in[2];
    const float* combine_w = (const float*)d_in[3];
    const float* combine_b = (const float*)d_in[4];
    const float* ln_g      = (const float*)d_in[5];
    const float* ln_b      = (const float*)d_in[6];
    const float* W1        = (const float*)d_in[7];
    const float* b1        = (const float*)d_in[8];
    const float* W2        = (const float*)d_in[9];
    const float* b2        = (const float*)d_in[10];
    float* out = (float*)d_out;

    float* y     = (float*)d_ws;         // NB*NC floats
    float* scale = y + NB * NC;          // NB*NC floats

    const int nblk = 2 * CB * NC;        // 8192 blocks (scale half + pool half)

    // Pipelined chunks: pool(c) ... attn(c) ... [scale(c) + pool(c+1)] ...
    pool_scale_kernel<<<nblk, 256, 0, stream>>>(x, scale, out, y, -1, 0);
    for (int c = 0; c < NB / CB; ++c) {
        const int b0 = c * CB;
        attn_kernel<<<CB, 1024, 0, stream>>>(y, conv1_w, conv2_w, combine_w, combine_b,
                                             ln_g, ln_b, W1, b1, W2, b2, scale, b0);
        const int b0_next = (c + 1 < NB / CB) ? (c + 1) * CB : -1;
        pool_scale_kernel<<<nblk, 256, 0, stream>>>(x, scale, out, y, b0, b0_next);
    }
}

// Round 4
// 133.020 us; speedup vs baseline: 1.3597x; 1.3597x over previous
//
#include <hip/hip_runtime.h>
#include <math.h>

#define NP 8      // paths
#define ND 128    // D = c / P
#define NC 1024   // channels = NP*ND
#define NL 4096   // sequence length
#define NB 16     // batch
#define LN_EPS 1e-5f

typedef float v4f __attribute__((ext_vector_type(4)));  // native vec: ok for nontemporal builtins

// ---------------- Kernel 1: global average pool over l ----------------
// One WAVE per (b,channel) row: 4096 blocks x 256 threads (4 waves/block).
__global__ __launch_bounds__(256) void pool_kernel(const float* __restrict__ x,
                                                   float* __restrict__ y) {
    const int wid  = threadIdx.x >> 6;
    const int lane = threadIdx.x & 63;
    const int row  = blockIdx.x * 4 + wid;          // 0 .. NB*NC-1
    const v4f* xr = (const v4f*)(x + (size_t)row * NL);
    float s = 0.f;
    #pragma unroll
    for (int i = 0; i < 16; ++i) {                  // 16*64 = 1024 float4 = row
        v4f v = xr[lane + i * 64];
        s += v.x + v.y + v.z + v.w;
    }
    #pragma unroll
    for (int off = 32; off; off >>= 1) s += __shfl_down(s, off, 64);
    if (lane == 0) y[row] = s * (1.f / NL);
}

// ---------------- Kernel 2: attn + gate -> scale ----------------
// One block per batch. 1024 threads = one per (p,d).
__global__ __launch_bounds__(1024) void attn_kernel(
    const float* __restrict__ y,
    const float* __restrict__ conv1_w,   // (NP,5)
    const float* __restrict__ conv2_w,   // (NP,9)
    const float* __restrict__ combine_w, // (2,)
    const float* __restrict__ combine_b, // scalar
    const float* __restrict__ ln_g, const float* __restrict__ ln_b,
    const float* __restrict__ W1, const float* __restrict__ b1,  // (NP,2NP),(2NP)
    const float* __restrict__ W2, const float* __restrict__ b2,  // (2NP,NP),(NP)
    float* __restrict__ scale)
{
    const int b = blockIdx.x;
    const int tid = threadIdx.x;
    const int p = tid >> 7;      // path
    const int d = tid & 127;     // position in D

    __shared__ float sy[NC];
    __shared__ float sattn[NC];
    __shared__ float sred[16];
    __shared__ float sgate[NP];

    sy[tid] = y[b * NC + tid];
    __syncthreads();

    const float* rowp = sy + p * ND;
    float c1 = 0.f;
    #pragma unroll
    for (int t = 0; t < 5; ++t) {
        int dd = d + t - 2;
        float v = (dd >= 0 && dd < ND) ? rowp[dd] : 0.f;
        c1 += conv1_w[p * 5 + t] * v;
    }
    float c2 = 0.f;
    #pragma unroll
    for (int t = 0; t < 9; ++t) {
        int dd = d + t - 4;
        float v = (dd >= 0 && dd < ND) ? rowp[dd] : 0.f;
        c2 += conv2_w[p * 9 + t] * v;
    }
    const float z = combine_w[0] * c1 + combine_w[1] * c2 + combine_b[0];
    const float a = 1.f / (1.f + expf(-z));
    sattn[tid] = a;

    // per-path mean of attn: each path = 2 consecutive waves of 64
    float r = a;
    #pragma unroll
    for (int off = 32; off; off >>= 1) r += __shfl_down(r, off, 64);
    const int lane = tid & 63, wid = tid >> 6;
    if (lane == 0) sred[wid] = r;
    __syncthreads();

    if (tid == 0) {
        float cross[NP];
        #pragma unroll
        for (int pp = 0; pp < NP; ++pp)
            cross[pp] = (sred[2 * pp] + sred[2 * pp + 1]) * (1.f / ND);
        float mu = 0.f;
        #pragma unroll
        for (int pp = 0; pp < NP; ++pp) mu += cross[pp];
        mu *= (1.f / NP);
        float var = 0.f;
        #pragma unroll
        for (int pp = 0; pp < NP; ++pp) { float dl = cross[pp] - mu; var += dl * dl; }
        var *= (1.f / NP);
        const float inv = rsqrtf(var + LN_EPS);
        float h[NP];
        #pragma unroll
        for (int pp = 0; pp < NP; ++pp)
            h[pp] = (cross[pp] - mu) * inv * ln_g[pp] + ln_b[pp];
        float h2[2 * NP];
        for (int j = 0; j < 2 * NP; ++j) {
            float s = b1[j];
            #pragma unroll
            for (int pp = 0; pp < NP; ++pp) s += h[pp] * W1[pp * (2 * NP) + j];
            h2[j] = 0.5f * s * (1.f + erff(s * 0.70710678118654752f));  // exact GELU
        }
        for (int pp = 0; pp < NP; ++pp) {
            float s = b2[pp];
            #pragma unroll
            for (int j = 0; j < 2 * NP; ++j) s += h2[j] * W2[j * NP + pp];
            sgate[pp] = 1.f / (1.f + expf(-s));
        }
    }
    __syncthreads();

    scale[b * NC + tid] = sattn[tid] * sgate[p];
}

// ---------------- Kernel 3: out = x * scale[row], nontemporal stores ----------
// nt stores don't allocate in L3 -> x (pulled in by pool_kernel) stays
// resident -> phase-3 x reads are L3 hits; HBM sees only the write stream.
__global__ __launch_bounds__(256) void scale_kernel(const float* __restrict__ x,
                                                    const float* __restrict__ scale,
                                                    float* __restrict__ out) {
    const v4f* xv = (const v4f*)x;
    v4f* ov = (v4f*)out;
    const size_t n = (size_t)NB * NC * (NL / 4);   // 16.7M float4
    const size_t stride = (size_t)gridDim.x * blockDim.x;
    for (size_t i = (size_t)blockIdx.x * blockDim.x + threadIdx.x; i < n; i += stride) {
        const float s = scale[i >> 10];            // NL/4 = 1024 float4 per row
        v4f v = xv[i];
        v *= s;
        __builtin_nontemporal_store(v, &ov[i]);
    }
}

extern "C" void kernel_launch(void* const* d_in, const int* in_sizes, int n_in,
                              void* d_out, int out_size, void* d_ws, size_t ws_size,
                              hipStream_t stream) {
    const float* x         = (const float*)d_in[0];
    const float* conv1_w   = (const float*)d_in[1];
    const float* conv2_w   = (const float*)d_in[2];
    const float* combine_w = (const float*)d_in[3];
    const float* combine_b = (const float*)d_in[4];
    const float* ln_g      = (const float*)d_in[5];
    const float* ln_b      = (const float*)d_in[6];
    const float* W1        = (const float*)d_in[7];
    const float* b1        = (const float*)d_in[8];
    const float* W2        = (const float*)d_in[9];
    const float* b2        = (const float*)d_in[10];
    float* out = (float*)d_out;

    float* y     = (float*)d_ws;         // NB*NC floats
    float* scale = y + NB * NC;          // NB*NC floats

    pool_kernel<<<NB * NC / 4, 256, 0, stream>>>(x, y);
    attn_kernel<<<NB, 1024, 0, stream>>>(y, conv1_w, conv2_w, combine_w, combine_b,
                                         ln_g, ln_b, W1, b1, W2, b2, scale);
    scale_kernel<<<2048, 256, 0, stream>>>(x, scale, out);
}